// Round 2
// baseline (1561.188 us; speedup 1.0000x reference)
//
#include <hip/hip_runtime.h>
#include <hip/hip_bf16.h>

// TrajGRU cell, B=8, Cin=8, Ch=64, H=W=128, L=5.
// Inputs f32, OUTPUT f32 (ref returns float32; out_npz ~31MB confirms).
// Pipeline:
//   A k_flowgen : f = tanh(conv5x5(x,w_i2f) + conv5x5(h,w_h2f))      [B,32,H,W] f32 (ws)
//   B k_flows   : flows = conv5x5(f,w_flows)                          [B,10,H,W] f32 (ws)
//   D k_warp    : warped[l*64+c] = bilinear(h[c], grid - flow_l)      [*,320,H,W] bf16 (ws)
//   E k_gate    : i2h conv3x3 (on the fly) + 1x1 ret-conv over warped + GRU gating -> out f32

#define HW 16384
#define W_ 128

__device__ __forceinline__ float sigmoidf_(float z) { return 1.f / (1.f + expf(-z)); }

// Accumulate a 5x5 same-pad conv over NIC input channels into acc[NOUT].
// Block = 256 threads covering a 16x16 output tile; s = 20*20 LDS staging buffer.
template <int NOUT, int NIC>
__device__ __forceinline__ void conv5x5_acc(const float* __restrict__ src0,
                                            const float* __restrict__ wgt,
                                            float* s, float (&acc)[NOUT],
                                            int ty0, int tx0, int lx, int ly) {
  for (int ic = 0; ic < NIC; ++ic) {
    const float* src = src0 + ((size_t)ic << 14);
    __syncthreads();
    for (int i = threadIdx.x; i < 400; i += 256) {
      int r = i / 20, c = i - r * 20;
      int gy = ty0 - 2 + r, gx = tx0 - 2 + c;
      s[i] = ((unsigned)gy < 128u && (unsigned)gx < 128u) ? src[gy * W_ + gx] : 0.f;
    }
    __syncthreads();
    float in[25];
#pragma unroll
    for (int t = 0; t < 25; ++t) in[t] = s[(ly + t / 5) * 20 + (lx + t % 5)];
#pragma unroll
    for (int o = 0; o < NOUT; ++o) {
      const float* w = wgt + ((size_t)(o * NIC + ic)) * 25;  // uniform -> s_load
      float a = acc[o];
#pragma unroll
      for (int t = 0; t < 25; ++t) a = fmaf(in[t], w[t], a);
      acc[o] = a;
    }
  }
}

__global__ __launch_bounds__(256) void k_flowgen(
    const float* __restrict__ x, const float* __restrict__ h,
    const float* __restrict__ w_i2f, const float* __restrict__ b_i2f,
    const float* __restrict__ w_h2f, const float* __restrict__ b_h2f,
    float* __restrict__ f) {
  const int b = blockIdx.y;
  const int ty0 = (blockIdx.x >> 3) << 4, tx0 = (blockIdx.x & 7) << 4;
  const int lx = threadIdx.x & 15, ly = threadIdx.x >> 4;
  __shared__ float s[400];
  float acc[32];
#pragma unroll
  for (int o = 0; o < 32; ++o) acc[o] = 0.f;

  conv5x5_acc<32, 8>(x + ((size_t)b * 8 << 14), w_i2f, s, acc, ty0, tx0, lx, ly);
  conv5x5_acc<32, 64>(h + ((size_t)b * 64 << 14), w_h2f, s, acc, ty0, tx0, lx, ly);

  const int p = (ty0 + ly) * W_ + tx0 + lx;
#pragma unroll
  for (int o = 0; o < 32; ++o)
    f[((size_t)(b * 32 + o) << 14) + p] = tanhf(acc[o] + b_i2f[o] + b_h2f[o]);
}

__global__ __launch_bounds__(256) void k_flows(
    const float* __restrict__ f, const float* __restrict__ w_flows,
    const float* __restrict__ b_flows, float* __restrict__ flows) {
  const int b = blockIdx.y;
  const int ty0 = (blockIdx.x >> 3) << 4, tx0 = (blockIdx.x & 7) << 4;
  const int lx = threadIdx.x & 15, ly = threadIdx.x >> 4;
  __shared__ float s[400];
  float acc[10];
#pragma unroll
  for (int o = 0; o < 10; ++o) acc[o] = 0.f;

  conv5x5_acc<10, 32>(f + ((size_t)b * 32 << 14), w_flows, s, acc, ty0, tx0, lx, ly);

  const int p = (ty0 + ly) * W_ + tx0 + lx;
#pragma unroll
  for (int o = 0; o < 10; ++o)
    flows[((size_t)(b * 10 + o) << 14) + p] = acc[o] + b_flows[o];
}

// warped[l*64+c][p] = bilinear border-clamped sample of h[b][c] at (x - fx, y - fy)
__global__ __launch_bounds__(256) void k_warp(
    const float* __restrict__ h, const float* __restrict__ flows,
    __hip_bfloat16* __restrict__ warped, int b0, int wstride) {
  const int b = b0 + blockIdx.z;
  __hip_bfloat16* wp = warped + (size_t)blockIdx.z * wstride;
  const int l = blockIdx.y;
  const int ty0 = (blockIdx.x >> 3) << 4, tx0 = (blockIdx.x & 7) << 4;
  const int lx = threadIdx.x & 15, ly = threadIdx.x >> 4;
  const int ox = tx0 + lx, oy = ty0 + ly;
  const int p = oy * W_ + ox;

  float fx = flows[((size_t)(b * 10 + 2 * l) << 14) + p];
  float fy = flows[((size_t)(b * 10 + 2 * l + 1) << 14) + p];
  float px = fminf(fmaxf((float)ox - fx, 0.f), 127.f);
  float py = fminf(fmaxf((float)oy - fy, 0.f), 127.f);
  float x0f = floorf(px), y0f = floorf(py);
  float wx = px - x0f, wy = py - y0f;
  int x0 = (int)x0f, y0 = (int)y0f;
  int x1 = min(x0 + 1, 127), y1 = min(y0 + 1, 127);
  float w00 = (1.f - wx) * (1.f - wy), w01 = wx * (1.f - wy);
  float w10 = (1.f - wx) * wy, w11 = wx * wy;
  int o00 = y0 * W_ + x0, o01 = y0 * W_ + x1;
  int o10 = y1 * W_ + x0, o11 = y1 * W_ + x1;

  const float* hb = h + ((size_t)(b * 64) << 14);
#pragma unroll 4
  for (int c = 0; c < 64; ++c) {
    const float* hp = hb + ((size_t)c << 14);
    float v = hp[o00] * w00 + hp[o01] * w01 + hp[o10] * w10 + hp[o11] * w11;
    wp[((size_t)(l * 64 + c) << 14) + p] = __float2bfloat16(v);
  }
}

// Fused: i2h 3x3 conv (8 ic) + 1x1 ret conv (320 ic over warped) + GRU gate.
// Block covers a 16x16 tile for 16 final channels (blockIdx.y = chunk 0..3).
__global__ __launch_bounds__(256) void k_gate(
    const float* __restrict__ x, const float* __restrict__ h,
    const float* __restrict__ w_i2h, const float* __restrict__ b_i2h,
    const float* __restrict__ w_ret, const float* __restrict__ b_ret,
    const __hip_bfloat16* __restrict__ warped,
    float* __restrict__ out, int b0, int wstride) {
  const int b = b0 + blockIdx.z;
  const __hip_bfloat16* wp = warped + (size_t)blockIdx.z * wstride;
  const int chunk = blockIdx.y;
  const int ty0 = (blockIdx.x >> 3) << 4, tx0 = (blockIdx.x & 7) << 4;
  const int lx = threadIdx.x & 15, ly = threadIdx.x >> 4;
  const int p = (ty0 + ly) * W_ + tx0 + lx;

  __shared__ float sx[8][324];  // 8 ic x 18x18 halo tile of x
  for (int i = threadIdx.x; i < 8 * 324; i += 256) {
    int ch = i / 324, r2 = i - ch * 324;
    int r = r2 / 18, c = r2 - r * 18;
    int gy = ty0 - 1 + r, gx = tx0 - 1 + c;
    sx[ch][r2] = ((unsigned)gy < 128u && (unsigned)gx < 128u)
                     ? x[((size_t)(b * 8 + ch) << 14) + gy * W_ + gx] : 0.f;
  }
  __syncthreads();

  float ar[16], au[16], ami[16], amh[16];
#pragma unroll
  for (int j = 0; j < 16; ++j) { ar[j] = 0.f; au[j] = 0.f; ami[j] = 0.f; amh[j] = 0.f; }

  // i2h: 3x3, pad 1
  for (int ic = 0; ic < 8; ++ic) {
    float in[9];
#pragma unroll
    for (int t = 0; t < 9; ++t) in[t] = sx[ic][(ly + t / 3) * 18 + (lx + t % 3)];
#pragma unroll
    for (int j = 0; j < 16; ++j) {
      const int c0 = chunk * 16 + j;
      const float* wr = w_i2h + ((size_t)(c0 * 8 + ic)) * 9;
      const float* wu = w_i2h + ((size_t)((64 + c0) * 8 + ic)) * 9;
      const float* wm = w_i2h + ((size_t)((128 + c0) * 8 + ic)) * 9;
      float a = ar[j], u = au[j], m = ami[j];
#pragma unroll
      for (int t = 0; t < 9; ++t) {
        a = fmaf(in[t], wr[t], a);
        u = fmaf(in[t], wu[t], u);
        m = fmaf(in[t], wm[t], m);
      }
      ar[j] = a; au[j] = u; ami[j] = m;
    }
  }

  // h2h: 1x1 conv over 320 warped channels
  for (int ic0 = 0; ic0 < 320; ic0 += 8) {
    float v[8];
#pragma unroll
    for (int k = 0; k < 8; ++k)
      v[k] = __bfloat162float(wp[((size_t)(ic0 + k) << 14) + p]);
#pragma unroll
    for (int j = 0; j < 16; ++j) {
      const int c0 = chunk * 16 + j;
      const float* wr = w_ret + (size_t)c0 * 320 + ic0;
      const float* wu = w_ret + (size_t)(64 + c0) * 320 + ic0;
      const float* wm = w_ret + (size_t)(128 + c0) * 320 + ic0;
      float a = ar[j], u = au[j], m = amh[j];
#pragma unroll
      for (int k = 0; k < 8; ++k) {
        a = fmaf(v[k], wr[k], a);
        u = fmaf(v[k], wu[k], u);
        m = fmaf(v[k], wm[k], m);
      }
      ar[j] = a; au[j] = u; amh[j] = m;
    }
  }

  // gating
#pragma unroll
  for (int j = 0; j < 16; ++j) {
    const int c0 = chunk * 16 + j;
    float r = sigmoidf_(ar[j] + b_i2h[c0] + b_ret[c0]);
    float u = sigmoidf_(au[j] + b_i2h[64 + c0] + b_ret[64 + c0]);
    float m = tanhf((ami[j] + b_i2h[128 + c0]) + r * (amh[j] + b_ret[128 + c0]));
    float hv = h[((size_t)(b * 64 + c0) << 14) + p];
    out[((size_t)(b * 64 + c0) << 14) + p] = u * hv + (1.f - u) * m;
  }
}

extern "C" void kernel_launch(void* const* d_in, const int* in_sizes, int n_in,
                              void* d_out, int out_size, void* d_ws, size_t ws_size,
                              hipStream_t stream) {
  const float* x       = (const float*)d_in[0];
  const float* h       = (const float*)d_in[1];
  const float* w_i2f   = (const float*)d_in[2];
  const float* b_i2f   = (const float*)d_in[3];
  const float* w_h2f   = (const float*)d_in[4];
  const float* b_h2f   = (const float*)d_in[5];
  const float* w_flows = (const float*)d_in[6];
  const float* b_flows = (const float*)d_in[7];
  const float* w_i2h   = (const float*)d_in[8];
  const float* b_i2h   = (const float*)d_in[9];
  const float* w_ret   = (const float*)d_in[10];
  const float* b_ret   = (const float*)d_in[11];
  float* out           = (float*)d_out;

  char* ws = (char*)d_ws;
  float* f = (float*)ws;                                  // 16 MB
  float* flows = (float*)(ws + 16777216);                 // 5 MB
  __hip_bfloat16* warped = (__hip_bfloat16*)(ws + 22020096);

  k_flowgen<<<dim3(64, 8), 256, 0, stream>>>(x, h, w_i2f, b_i2f, w_h2f, b_h2f, f);
  k_flows<<<dim3(64, 8), 256, 0, stream>>>(f, w_flows, b_flows, flows);

  const size_t full_need = 22020096ull + 8ull * 320 * HW * 2;  // ~101 MB
  if (ws_size >= full_need) {
    // full-batch warped buffer: best occupancy
    k_warp<<<dim3(64, 5, 8), 256, 0, stream>>>(h, flows, warped, 0, 320 * HW);
    k_gate<<<dim3(64, 4, 8), 256, 0, stream>>>(x, h, w_i2h, b_i2h, w_ret, b_ret,
                                               warped, out, 0, 320 * HW);
  } else {
    // per-batch warped slot (10 MB), stream-serialized reuse
    for (int b = 0; b < 8; ++b) {
      k_warp<<<dim3(64, 5, 1), 256, 0, stream>>>(h, flows, warped, b, 0);
      k_gate<<<dim3(64, 4, 1), 256, 0, stream>>>(x, h, w_i2h, b_i2h, w_ret, b_ret,
                                                 warped, out, b, 0);
    }
  }
}

// Round 4
// 985.369 us; speedup vs baseline: 1.5844x; 1.5844x over previous
//
#include <hip/hip_runtime.h>
#include <hip/hip_bf16.h>

// TrajGRU cell, B=8, Cin=8, Ch=64, H=W=128, L=5. Inputs f32, OUTPUT f32.
// Pipeline:
//   k_flowgen : f = tanh(conv5x5(x,w_i2f)+conv5x5(h,w_h2f))   [B,32,H,W] f32
//   k_flows   : flows = conv5x5(f,w_flows)                     [B,10,H,W] f32
//   k_prep    : w_ret f32 -> MFMA-fragment-packed bf16 [12][10][64][8]
//   k_warp    : warped_T[b][p][l*64+c] = bilinear(h)           bf16 pixel-major
//   k_i2h     : i2h_T[b][p][192] = conv3x3(x,w_i2h) (no bias)  f32
//   k_gemm    : MFMA 16x16x32 bf16 GEMM (h2h) + fused GRU gating -> out f32
//
// ws sizes (exact): warped = NB*10,485,760 B; i2h = NB*12,582,912 B;
// packed = 122,880 B; f = 16,777,216 B; flows = 5,242,880 B.
// NB=4 total: 40MB + 48MB (f overlays) + packed + flows = 97,640,448 B
//   (fits the proven >=105,906,176 B workspace).
// NB=8 total: 184,672,256 B (only if ws_size allows).

#define HW 16384
#define W_ 128

typedef __attribute__((ext_vector_type(8))) short short8;
typedef __attribute__((ext_vector_type(4))) float f32x4;

__device__ __forceinline__ float sigmoidf_(float z) { return 1.f / (1.f + expf(-z)); }

template <int NOUT, int NIC>
__device__ __forceinline__ void conv5x5_acc(const float* __restrict__ src0,
                                            const float* __restrict__ wgt,
                                            float* s, float (&acc)[NOUT],
                                            int ty0, int tx0, int lx, int ly) {
  for (int ic = 0; ic < NIC; ++ic) {
    const float* src = src0 + ((size_t)ic << 14);
    __syncthreads();
    for (int i = threadIdx.x; i < 400; i += 256) {
      int r = i / 20, c = i - r * 20;
      int gy = ty0 - 2 + r, gx = tx0 - 2 + c;
      s[i] = ((unsigned)gy < 128u && (unsigned)gx < 128u) ? src[gy * W_ + gx] : 0.f;
    }
    __syncthreads();
    float in[25];
#pragma unroll
    for (int t = 0; t < 25; ++t) in[t] = s[(ly + t / 5) * 20 + (lx + t % 5)];
#pragma unroll
    for (int o = 0; o < NOUT; ++o) {
      const float* w = wgt + ((size_t)(o * NIC + ic)) * 25;  // uniform -> s_load
      float a = acc[o];
#pragma unroll
      for (int t = 0; t < 25; ++t) a = fmaf(in[t], w[t], a);
      acc[o] = a;
    }
  }
}

__global__ __launch_bounds__(256) void k_flowgen(
    const float* __restrict__ x, const float* __restrict__ h,
    const float* __restrict__ w_i2f, const float* __restrict__ b_i2f,
    const float* __restrict__ w_h2f, const float* __restrict__ b_h2f,
    float* __restrict__ f) {
  const int b = blockIdx.y;
  const int ty0 = (blockIdx.x >> 3) << 4, tx0 = (blockIdx.x & 7) << 4;
  const int lx = threadIdx.x & 15, ly = threadIdx.x >> 4;
  __shared__ float s[400];
  float acc[32];
#pragma unroll
  for (int o = 0; o < 32; ++o) acc[o] = 0.f;

  conv5x5_acc<32, 8>(x + ((size_t)b * 8 << 14), w_i2f, s, acc, ty0, tx0, lx, ly);
  conv5x5_acc<32, 64>(h + ((size_t)b * 64 << 14), w_h2f, s, acc, ty0, tx0, lx, ly);

  const int p = (ty0 + ly) * W_ + tx0 + lx;
#pragma unroll
  for (int o = 0; o < 32; ++o)
    f[((size_t)(b * 32 + o) << 14) + p] = tanhf(acc[o] + b_i2f[o] + b_h2f[o]);
}

__global__ __launch_bounds__(256) void k_flows(
    const float* __restrict__ f, const float* __restrict__ w_flows,
    const float* __restrict__ b_flows, float* __restrict__ flows) {
  const int b = blockIdx.y;
  const int ty0 = (blockIdx.x >> 3) << 4, tx0 = (blockIdx.x & 7) << 4;
  const int lx = threadIdx.x & 15, ly = threadIdx.x >> 4;
  __shared__ float s[400];
  float acc[10];
#pragma unroll
  for (int o = 0; o < 10; ++o) acc[o] = 0.f;

  conv5x5_acc<10, 32>(f + ((size_t)b * 32 << 14), w_flows, s, acc, ty0, tx0, lx, ly);

  const int p = (ty0 + ly) * W_ + tx0 + lx;
#pragma unroll
  for (int o = 0; o < 10; ++o)
    flows[((size_t)(b * 10 + o) << 14) + p] = acc[o] + b_flows[o];
}

// packed[((mt*10+ks)*64+l)*8+i] = bf16(w_ret[(mt*16+(l&15))*320 + ks*32+(l>>4)*8+i])
__global__ void k_prep(const float* __restrict__ w_ret,
                       __hip_bfloat16* __restrict__ packed) {
  int t = blockIdx.x * 256 + threadIdx.x;
  if (t >= 61440) return;
  int i = t & 7, l = (t >> 3) & 63, ks = (t >> 9) % 10, mt = t / 5120;
  int m = mt * 16 + (l & 15), k = ks * 32 + ((l >> 4) << 3) + i;
  packed[t] = __float2bfloat16(w_ret[(size_t)m * 320 + k]);
}

// warped[bz][p][l*64+c] = bilinear border-clamped sample of h[b][c] at (x-fx, y-fy)
__global__ __launch_bounds__(256) void k_warp(
    const float* __restrict__ h, const float* __restrict__ flows,
    __hip_bfloat16* __restrict__ warped, int b0) {
  const int bz = blockIdx.z, b = b0 + bz;
  const int l = blockIdx.y;
  const int ty0 = (blockIdx.x >> 3) << 4, tx0 = (blockIdx.x & 7) << 4;
  const int lx = threadIdx.x & 15, ly = threadIdx.x >> 4;
  const int ox = tx0 + lx, oy = ty0 + ly;
  const int p = oy * W_ + ox;

  float fx = flows[((size_t)(b * 10 + 2 * l) << 14) + p];
  float fy = flows[((size_t)(b * 10 + 2 * l + 1) << 14) + p];
  float px = fminf(fmaxf((float)ox - fx, 0.f), 127.f);
  float py = fminf(fmaxf((float)oy - fy, 0.f), 127.f);
  float x0f = floorf(px), y0f = floorf(py);
  float wx = px - x0f, wy = py - y0f;
  int x0 = (int)x0f, y0 = (int)y0f;
  int x1 = min(x0 + 1, 127), y1 = min(y0 + 1, 127);
  float w00 = (1.f - wx) * (1.f - wy), w01 = wx * (1.f - wy);
  float w10 = (1.f - wx) * wy, w11 = wx * wy;
  int o00 = y0 * W_ + x0, o01 = y0 * W_ + x1;
  int o10 = y1 * W_ + x0, o11 = y1 * W_ + x1;

  const float* hb = h + ((size_t)(b * 64) << 14);
  __hip_bfloat16* wp = warped + ((size_t)bz * HW + p) * 320 + l * 64;
  for (int c0 = 0; c0 < 64; c0 += 8) {
    short8 pack;
#pragma unroll
    for (int k = 0; k < 8; ++k) {
      const float* hp = hb + ((size_t)(c0 + k) << 14);
      float v = hp[o00] * w00 + hp[o01] * w01 + hp[o10] * w10 + hp[o11] * w11;
      __hip_bfloat16 bv = __float2bfloat16(v);
      pack[k] = (short)*reinterpret_cast<unsigned short*>(&bv);
    }
    *reinterpret_cast<short8*>(wp + c0) = pack;
  }
}

// i2h_T[bz][p][c_lin] = conv3x3(x, w_i2h[c_lin]) (no bias), c_lin = chunk*16+j
__global__ __launch_bounds__(256) void k_i2h(
    const float* __restrict__ x, const float* __restrict__ w_i2h,
    float* __restrict__ i2h, int b0) {
  const int bz = blockIdx.z, b = b0 + bz;
  const int chunk = blockIdx.y;  // 0..11
  const int ty0 = (blockIdx.x >> 3) << 4, tx0 = (blockIdx.x & 7) << 4;
  const int lx = threadIdx.x & 15, ly = threadIdx.x >> 4;

  __shared__ float sx[8][324];  // 18x18 halo tile
  for (int i = threadIdx.x; i < 8 * 324; i += 256) {
    int ch = i / 324, r2 = i - ch * 324;
    int r = r2 / 18, c = r2 - r * 18;
    int gy = ty0 - 1 + r, gx = tx0 - 1 + c;
    sx[ch][r2] = ((unsigned)gy < 128u && (unsigned)gx < 128u)
                     ? x[((size_t)(b * 8 + ch) << 14) + gy * W_ + gx] : 0.f;
  }
  __syncthreads();

  float acc[16];
#pragma unroll
  for (int j = 0; j < 16; ++j) acc[j] = 0.f;

  for (int ic = 0; ic < 8; ++ic) {
    float in[9];
#pragma unroll
    for (int t = 0; t < 9; ++t) in[t] = sx[ic][(ly + t / 3) * 18 + (lx + t % 3)];
#pragma unroll
    for (int j = 0; j < 16; ++j) {
      const float* w = w_i2h + ((size_t)((chunk * 16 + j) * 8 + ic)) * 9;  // uniform
      float a = acc[j];
#pragma unroll
      for (int t = 0; t < 9; ++t) a = fmaf(in[t], w[t], a);
      acc[j] = a;
    }
  }

  const int p = (ty0 + ly) * W_ + tx0 + lx;
  float* op = i2h + ((size_t)bz * HW + p) * 192 + chunk * 16;
#pragma unroll
  for (int q = 0; q < 4; ++q) {
    f32x4 v = {acc[4 * q], acc[4 * q + 1], acc[4 * q + 2], acc[4 * q + 3]};
    *reinterpret_cast<f32x4*>(op + 4 * q) = v;
  }
}

// GEMM C[P=16384][M=192] = warped_T[P][320] x w_ret^T[320][192], + fused gating.
// Block: 256 thr (4 waves), 64-pixel x 192-channel tile. Wave wv: channels
// c = wv*16+lr for all 3 gates (mo-tiles wv, 4+wv, 8+wv), all 4 pixel-subtiles.
__global__ __launch_bounds__(256) void k_gemm_gate(
    const __hip_bfloat16* __restrict__ warped,
    const __hip_bfloat16* __restrict__ packed,
    const float* __restrict__ i2h, const float* __restrict__ h,
    const float* __restrict__ b_i2h, const float* __restrict__ b_ret,
    float* __restrict__ out, int b0) {
  const int bz = blockIdx.z, b = b0 + bz;
  const int p0 = blockIdx.x << 6;
  const int wv = threadIdx.x >> 6, l = threadIdx.x & 63;
  const int lr = l & 15, lq = l >> 4;

  f32x4 acc[3][4];
#pragma unroll
  for (int g = 0; g < 3; ++g)
#pragma unroll
    for (int t = 0; t < 4; ++t) acc[g][t] = {0.f, 0.f, 0.f, 0.f};

  // A: lane holds warped[pixel = p0+pt*16+lr][k = ks*32 + lq*8 + 0..7]
  const short8* ap0 = reinterpret_cast<const short8*>(
      warped + ((size_t)bz * HW + p0 + lr) * 320 + lq * 8);
  // B: packed fragment stream, mt = g*4+wv
  const short8* bp0 = reinterpret_cast<const short8*>(packed) + (size_t)wv * 640 + l;

  for (int ks = 0; ks < 10; ++ks) {
    short8 af[4];
#pragma unroll
    for (int pt = 0; pt < 4; ++pt) af[pt] = ap0[pt * 640 + ks * 4];
    short8 bf[3];
#pragma unroll
    for (int g = 0; g < 3; ++g) bf[g] = bp0[g * 2560 + ks * 64];
#pragma unroll
    for (int g = 0; g < 3; ++g)
#pragma unroll
      for (int pt = 0; pt < 4; ++pt)
        acc[g][pt] = __builtin_amdgcn_mfma_f32_16x16x32_bf16(af[pt], bf[g],
                                                             acc[g][pt], 0, 0, 0);
  }

  // Epilogue: D row = pixel offset (lq*4+reg), D col = channel (lr). Fused GRU.
  const int c = wv * 16 + lr;
  const float bir = b_i2h[c], biu = b_i2h[64 + c], bim = b_i2h[128 + c];
  const float brr = b_ret[c], bru = b_ret[64 + c], brm = b_ret[128 + c];
  const float* hb = h + ((size_t)(b * 64 + c) << 14);
  float* ob = out + ((size_t)(b * 64 + c) << 14);
#pragma unroll
  for (int pt = 0; pt < 4; ++pt) {
#pragma unroll
    for (int r = 0; r < 4; ++r) {
      const int pixel = p0 + pt * 16 + lq * 4 + r;
      const float* ip = i2h + ((size_t)bz * HW + pixel) * 192;
      float rg = sigmoidf_(acc[0][pt][r] + ip[c] + bir + brr);
      float ug = sigmoidf_(acc[1][pt][r] + ip[64 + c] + biu + bru);
      float mg = tanhf((ip[128 + c] + bim) + rg * (acc[2][pt][r] + brm));
      ob[pixel] = ug * hb[pixel] + (1.f - ug) * mg;
    }
  }
}

extern "C" void kernel_launch(void* const* d_in, const int* in_sizes, int n_in,
                              void* d_out, int out_size, void* d_ws, size_t ws_size,
                              hipStream_t stream) {
  const float* x       = (const float*)d_in[0];
  const float* h       = (const float*)d_in[1];
  const float* w_i2f   = (const float*)d_in[2];
  const float* b_i2f   = (const float*)d_in[3];
  const float* w_h2f   = (const float*)d_in[4];
  const float* b_h2f   = (const float*)d_in[5];
  const float* w_flows = (const float*)d_in[6];
  const float* b_flows = (const float*)d_in[7];
  const float* w_i2h   = (const float*)d_in[8];
  const float* b_i2h   = (const float*)d_in[9];
  const float* w_ret   = (const float*)d_in[10];
  const float* b_ret   = (const float*)d_in[11];
  float* out           = (float*)d_out;
  char* ws = (char*)d_ws;

  auto run = [&](int NB, size_t off_warped, size_t off_i2h, size_t off_packed,
                 size_t off_f, size_t off_flows) {
    float* f = (float*)(ws + off_f);
    float* flows = (float*)(ws + off_flows);
    __hip_bfloat16* warped = (__hip_bfloat16*)(ws + off_warped);
    float* i2hb = (float*)(ws + off_i2h);
    __hip_bfloat16* packed = (__hip_bfloat16*)(ws + off_packed);
    k_flowgen<<<dim3(64, 8), 256, 0, stream>>>(x, h, w_i2f, b_i2f, w_h2f, b_h2f, f);
    k_flows<<<dim3(64, 8), 256, 0, stream>>>(f, w_flows, b_flows, flows);
    k_prep<<<240, 256, 0, stream>>>(w_ret, packed);
    for (int b0 = 0; b0 < 8; b0 += NB) {
      k_warp<<<dim3(64, 5, NB), 256, 0, stream>>>(h, flows, warped, b0);
      k_i2h<<<dim3(64, 12, NB), 256, 0, stream>>>(x, w_i2h, i2hb, b0);
      k_gemm_gate<<<dim3(256, 1, NB), 256, 0, stream>>>(warped, packed, i2hb, h,
                                                        b_i2h, b_ret, out, b0);
    }
  };

  if (ws_size >= 184672256ull) {
    // NB=8: [warped 83,886,080][i2h 100,663,296][packed 122,880]
    // f (16MB) + flows (5MB) overlay the i2h region (single iteration:
    // flows' last read (k_warp) precedes k_i2h's write in stream order).
    run(8, 0, 83886080, 184549376, 83886080, 100663296);
  } else {
    // NB=4 (fits proven >=105.9MB ws): [warped 41,943,040][i2h 50,331,648]
    // [packed @92,274,688][flows @92,397,568, persists across iterations]
    // f overlays i2h (dead after k_flows). Total 97,640,448.
    run(4, 0, 41943040, 92274688, 41943040, 92397568);
  }
}

// Round 5
// 474.734 us; speedup vs baseline: 3.2886x; 2.0756x over previous
//
#include <hip/hip_runtime.h>
#include <hip/hip_bf16.h>

// TrajGRU cell, B=8, Cin=8, Ch=64, H=W=128, L=5. Inputs f32, OUTPUT f32.
// All matmul-shaped work on bf16 MFMA (16x16x32):
//   k_transpose    : cat_T[b][p][96] = [h(64ch), x(8ch), 0-pad(24)] bf16 pixel-major
//   k_prep_fg/fl/ret: weights -> MFMA-fragment-packed bf16
//   k_flowgen_mfma : f_T[b][p][32] = tanh(25-tap implicit GEMM over cat_T)  bf16
//   k_flows_mfma   : flows[b][10][p] = 25-tap implicit GEMM over f_T        f32
//   k_warp         : warped_T[b][p][320] = bilinear(h, grid-flow)           bf16
//   k_i2h          : i2h_T[b][p][192] = conv3x3(x) (no bias)                f32
//   k_gemm_gate    : h2h 1x1 GEMM (K=320) + fused GRU gating -> out         f32
//
// ws layout (proven ws_size >= 134,340,608 from R2):
//   [0)            cat_T 25,165,824 | f_T @25,165,824 (8,388,608)   (dead after flows)
//   [0)            warped 41,943,040 (NB=4, overwrites cat_T/f_T)
//   [41,943,040)   i2h 50,331,648
//   [92,274,688)   flows 5,242,880
//   [97,517,568)   packed_ret 122,880
//   [97,640,448)   packed_fg 153,600
//   [97,794,048)   packed_fl 25,600      -> end 97,819,648

#define HW 16384
#define W_ 128

typedef __attribute__((ext_vector_type(8))) short short8;
typedef __attribute__((ext_vector_type(4))) float f32x4;

__device__ __forceinline__ float sigmoidf_(float z) { return 1.f / (1.f + expf(-z)); }

__device__ __forceinline__ short bf16bits(float v) {
  __hip_bfloat16 bv = __float2bfloat16(v);
  return (short)*reinterpret_cast<unsigned short*>(&bv);
}

// ---- cat_T[b][p][96]: ch 0-63 = h, 64-71 = x, 72-95 = 0. Wave wv handles 24 ch.
__global__ __launch_bounds__(256) void k_transpose(
    const float* __restrict__ h, const float* __restrict__ x,
    __hip_bfloat16* __restrict__ cat) {
  const int b = blockIdx.y;
  const int wv = threadIdx.x >> 6, l = threadIdx.x & 63;
  const int p = blockIdx.x * 64 + l;
  const int c0 = wv * 24;
  short8 v[3];
#pragma unroll
  for (int q = 0; q < 3; ++q)
#pragma unroll
    for (int k = 0; k < 8; ++k) {
      int c = c0 + q * 8 + k;
      float val = 0.f;
      if (c < 64)      val = h[((size_t)(b * 64 + c) << 14) + p];
      else if (c < 72) val = x[((size_t)(b * 8 + (c - 64)) << 14) + p];
      v[q][k] = bf16bits(val);
    }
  short8* dst = reinterpret_cast<short8*>(cat + ((size_t)b * HW + p) * 96 + c0);
#pragma unroll
  for (int q = 0; q < 3; ++q) dst[q] = v[q];
}

// ---- flowgen weights: pfg[(((tap*3+ks)*2+ot)*64+l)*8+i]
//      = bf16(w[oc=ot*16+(l&15)][k=ks*32+(l>>4)*8+i][tap]), k: 0-63 h2f, 64-71 i2f, else 0
__global__ void k_prep_fg(const float* __restrict__ w_i2f,
                          const float* __restrict__ w_h2f,
                          __hip_bfloat16* __restrict__ pfg) {
  int t = blockIdx.x * 256 + threadIdx.x;
  if (t >= 76800) return;
  int i = t & 7, l = (t >> 3) & 63, ot = (t >> 9) & 1, r = t >> 10;
  int ks = r % 3, tap = r / 3;
  int oc = ot * 16 + (l & 15), k = ks * 32 + ((l >> 4) << 3) + i;
  float v = 0.f;
  if (k < 64)      v = w_h2f[(size_t)(oc * 64 + k) * 25 + tap];
  else if (k < 72) v = w_i2f[(size_t)(oc * 8 + (k - 64)) * 25 + tap];
  pfg[t] = __float2bfloat16(v);
}

// ---- flows weights: pfl[((tap*64)+l)*8+i] = bf16(w_flows[oc=l&15][k=(l>>4)*8+i][tap]), oc<10
__global__ void k_prep_fl(const float* __restrict__ w_flows,
                          __hip_bfloat16* __restrict__ pfl) {
  int t = blockIdx.x * 256 + threadIdx.x;
  if (t >= 12800) return;
  int i = t & 7, l = (t >> 3) & 63, tap = t >> 9;
  int oc = l & 15, k = ((l >> 4) << 3) + i;
  pfl[t] = __float2bfloat16(oc < 10 ? w_flows[(size_t)(oc * 32 + k) * 25 + tap] : 0.f);
}

// ---- w_ret: packed[((mt*10+ks)*64+l)*8+i] (validated R4)
__global__ void k_prep(const float* __restrict__ w_ret,
                       __hip_bfloat16* __restrict__ packed) {
  int t = blockIdx.x * 256 + threadIdx.x;
  if (t >= 61440) return;
  int i = t & 7, l = (t >> 3) & 63, ks = (t >> 9) % 10, mt = t / 5120;
  int m = mt * 16 + (l & 15), k = ks * 32 + ((l >> 4) << 3) + i;
  packed[t] = __float2bfloat16(w_ret[(size_t)m * 320 + k]);
}

// ---- flowgen: 25-tap implicit GEMM, K=96 (3 steps), M=64px/block, N=32oc.
// Block 4 waves; wave wv: pixels x0+wv*16..+15, both oc-tiles.
__global__ __launch_bounds__(256) void k_flowgen_mfma(
    const __hip_bfloat16* __restrict__ cat, const __hip_bfloat16* __restrict__ pfg,
    const float* __restrict__ b_i2f, const float* __restrict__ b_h2f,
    __hip_bfloat16* __restrict__ f_T) {
  const int b = blockIdx.y;
  const int y = blockIdx.x >> 1, x0 = (blockIdx.x & 1) << 6;
  const int wv = threadIdx.x >> 6, l = threadIdx.x & 63;
  const int lr = l & 15, lq = l >> 4;
  const int xa = x0 + wv * 16 + lr;  // A-load pixel x
  const size_t cb = (size_t)b * HW * 96;
  const short8* pf = reinterpret_cast<const short8*>(pfg);
  const short8 z8 = {0, 0, 0, 0, 0, 0, 0, 0};

  f32x4 acc[2] = {{0.f, 0.f, 0.f, 0.f}, {0.f, 0.f, 0.f, 0.f}};

  for (int tap = 0; tap < 25; ++tap) {
    const int dy = tap / 5 - 2, dx = tap % 5 - 2;
    const int yy = y + dy;
    if ((unsigned)yy >= 128u) continue;  // block-uniform
    const int xx = xa + dx;
    const bool ok = (unsigned)xx < 128u;
    const short8* ap = reinterpret_cast<const short8*>(cat + cb + (size_t)(yy * W_ + xx) * 96) + lq;
#pragma unroll
    for (int ks = 0; ks < 3; ++ks) {
      short8 af = ok ? ap[ks * 4] : z8;
#pragma unroll
      for (int ot = 0; ot < 2; ++ot) {
        short8 bf = pf[(size_t)(((tap * 3 + ks) << 1) + ot) * 64 + l];
        acc[ot] = __builtin_amdgcn_mfma_f32_16x16x32_bf16(af, bf, acc[ot], 0, 0, 0);
      }
    }
  }

  // D: pixel = x0+wv*16+lq*4+r, oc = ot*16+lr
  const int pbase = y * W_ + x0 + wv * 16 + lq * 4;
#pragma unroll
  for (int ot = 0; ot < 2; ++ot) {
    const int oc = ot * 16 + lr;
    const float bias = b_i2f[oc] + b_h2f[oc];
#pragma unroll
    for (int r = 0; r < 4; ++r)
      f_T[((size_t)b * HW + pbase + r) * 32 + oc] =
          __float2bfloat16(tanhf(acc[ot][r] + bias));
  }
}

// ---- flows: 25-tap implicit GEMM, K=32 (1 step), N=16 (10 used). Wave = 16 px.
__global__ __launch_bounds__(256) void k_flows_mfma(
    const __hip_bfloat16* __restrict__ f_T, const __hip_bfloat16* __restrict__ pfl,
    const float* __restrict__ b_flows, float* __restrict__ flows) {
  const int b = blockIdx.y;
  const int y = blockIdx.x >> 1, x0 = (blockIdx.x & 1) << 6;
  const int wv = threadIdx.x >> 6, l = threadIdx.x & 63;
  const int lr = l & 15, lq = l >> 4;
  const int xa = x0 + wv * 16 + lr;
  const short8* pf = reinterpret_cast<const short8*>(pfl);
  const short8 z8 = {0, 0, 0, 0, 0, 0, 0, 0};

  f32x4 acc = {0.f, 0.f, 0.f, 0.f};

  for (int tap = 0; tap < 25; ++tap) {
    const int dy = tap / 5 - 2, dx = tap % 5 - 2;
    const int yy = y + dy;
    if ((unsigned)yy >= 128u) continue;
    const int xx = xa + dx;
    short8 af = ((unsigned)xx < 128u)
        ? *reinterpret_cast<const short8*>(f_T + ((size_t)b * HW + yy * W_ + xx) * 32 + lq * 8)
        : z8;
    short8 bf = pf[tap * 64 + l];
    acc = __builtin_amdgcn_mfma_f32_16x16x32_bf16(af, bf, acc, 0, 0, 0);
  }

  if (lr < 10) {
    const float bb = b_flows[lr];
    const int p = y * W_ + x0 + wv * 16 + lq * 4;
    f32x4 v = {acc[0] + bb, acc[1] + bb, acc[2] + bb, acc[3] + bb};
    *reinterpret_cast<f32x4*>(flows + ((size_t)(b * 10 + lr) << 14) + p) = v;
  }
}

// ---- warp (unchanged, validated)
__global__ __launch_bounds__(256) void k_warp(
    const float* __restrict__ h, const float* __restrict__ flows,
    __hip_bfloat16* __restrict__ warped, int b0) {
  const int bz = blockIdx.z, b = b0 + bz;
  const int l = blockIdx.y;
  const int ty0 = (blockIdx.x >> 3) << 4, tx0 = (blockIdx.x & 7) << 4;
  const int lx = threadIdx.x & 15, ly = threadIdx.x >> 4;
  const int ox = tx0 + lx, oy = ty0 + ly;
  const int p = oy * W_ + ox;

  float fx = flows[((size_t)(b * 10 + 2 * l) << 14) + p];
  float fy = flows[((size_t)(b * 10 + 2 * l + 1) << 14) + p];
  float px = fminf(fmaxf((float)ox - fx, 0.f), 127.f);
  float py = fminf(fmaxf((float)oy - fy, 0.f), 127.f);
  float x0f = floorf(px), y0f = floorf(py);
  float wx = px - x0f, wy = py - y0f;
  int x0 = (int)x0f, y0 = (int)y0f;
  int x1 = min(x0 + 1, 127), y1 = min(y0 + 1, 127);
  float w00 = (1.f - wx) * (1.f - wy), w01 = wx * (1.f - wy);
  float w10 = (1.f - wx) * wy, w11 = wx * wy;
  int o00 = y0 * W_ + x0, o01 = y0 * W_ + x1;
  int o10 = y1 * W_ + x0, o11 = y1 * W_ + x1;

  const float* hb = h + ((size_t)(b * 64) << 14);
  __hip_bfloat16* wp = warped + ((size_t)bz * HW + p) * 320 + l * 64;
  for (int c0 = 0; c0 < 64; c0 += 8) {
    short8 pack;
#pragma unroll
    for (int k = 0; k < 8; ++k) {
      const float* hp = hb + ((size_t)(c0 + k) << 14);
      pack[k] = bf16bits(hp[o00] * w00 + hp[o01] * w01 + hp[o10] * w10 + hp[o11] * w11);
    }
    *reinterpret_cast<short8*>(wp + c0) = pack;
  }
}

// ---- i2h 3x3 (unchanged, validated)
__global__ __launch_bounds__(256) void k_i2h(
    const float* __restrict__ x, const float* __restrict__ w_i2h,
    float* __restrict__ i2h, int b0) {
  const int bz = blockIdx.z, b = b0 + bz;
  const int chunk = blockIdx.y;  // 0..11
  const int ty0 = (blockIdx.x >> 3) << 4, tx0 = (blockIdx.x & 7) << 4;
  const int lx = threadIdx.x & 15, ly = threadIdx.x >> 4;

  __shared__ float sx[8][324];
  for (int i = threadIdx.x; i < 8 * 324; i += 256) {
    int ch = i / 324, r2 = i - ch * 324;
    int r = r2 / 18, c = r2 - r * 18;
    int gy = ty0 - 1 + r, gx = tx0 - 1 + c;
    sx[ch][r2] = ((unsigned)gy < 128u && (unsigned)gx < 128u)
                     ? x[((size_t)(b * 8 + ch) << 14) + gy * W_ + gx] : 0.f;
  }
  __syncthreads();

  float acc[16];
#pragma unroll
  for (int j = 0; j < 16; ++j) acc[j] = 0.f;

  for (int ic = 0; ic < 8; ++ic) {
    float in[9];
#pragma unroll
    for (int t = 0; t < 9; ++t) in[t] = sx[ic][(ly + t / 3) * 18 + (lx + t % 3)];
#pragma unroll
    for (int j = 0; j < 16; ++j) {
      const float* w = w_i2h + ((size_t)((chunk * 16 + j) * 8 + ic)) * 9;
      float a = acc[j];
#pragma unroll
      for (int t = 0; t < 9; ++t) a = fmaf(in[t], w[t], a);
      acc[j] = a;
    }
  }

  const int p = (ty0 + ly) * W_ + tx0 + lx;
  float* op = i2h + ((size_t)bz * HW + p) * 192 + chunk * 16;
#pragma unroll
  for (int q = 0; q < 4; ++q) {
    f32x4 v = {acc[4 * q], acc[4 * q + 1], acc[4 * q + 2], acc[4 * q + 3]};
    *reinterpret_cast<f32x4*>(op + 4 * q) = v;
  }
}

// ---- h2h GEMM + gating (unchanged, validated)
__global__ __launch_bounds__(256) void k_gemm_gate(
    const __hip_bfloat16* __restrict__ warped,
    const __hip_bfloat16* __restrict__ packed,
    const float* __restrict__ i2h, const float* __restrict__ h,
    const float* __restrict__ b_i2h, const float* __restrict__ b_ret,
    float* __restrict__ out, int b0) {
  const int bz = blockIdx.z, b = b0 + bz;
  const int p0 = blockIdx.x << 6;
  const int wv = threadIdx.x >> 6, l = threadIdx.x & 63;
  const int lr = l & 15, lq = l >> 4;

  f32x4 acc[3][4];
#pragma unroll
  for (int g = 0; g < 3; ++g)
#pragma unroll
    for (int t = 0; t < 4; ++t) acc[g][t] = {0.f, 0.f, 0.f, 0.f};

  const short8* ap0 = reinterpret_cast<const short8*>(
      warped + ((size_t)bz * HW + p0 + lr) * 320 + lq * 8);
  const short8* bp0 = reinterpret_cast<const short8*>(packed) + (size_t)wv * 640 + l;

  for (int ks = 0; ks < 10; ++ks) {
    short8 af[4];
#pragma unroll
    for (int pt = 0; pt < 4; ++pt) af[pt] = ap0[pt * 640 + ks * 4];
    short8 bf[3];
#pragma unroll
    for (int g = 0; g < 3; ++g) bf[g] = bp0[g * 2560 + ks * 64];
#pragma unroll
    for (int g = 0; g < 3; ++g)
#pragma unroll
      for (int pt = 0; pt < 4; ++pt)
        acc[g][pt] = __builtin_amdgcn_mfma_f32_16x16x32_bf16(af[pt], bf[g],
                                                             acc[g][pt], 0, 0, 0);
  }

  const int c = wv * 16 + lr;
  const float bir = b_i2h[c], biu = b_i2h[64 + c], bim = b_i2h[128 + c];
  const float brr = b_ret[c], bru = b_ret[64 + c], brm = b_ret[128 + c];
  const float* hb = h + ((size_t)(b * 64 + c) << 14);
  float* ob = out + ((size_t)(b * 64 + c) << 14);
#pragma unroll
  for (int pt = 0; pt < 4; ++pt) {
#pragma unroll
    for (int r = 0; r < 4; ++r) {
      const int pixel = p0 + pt * 16 + lq * 4 + r;
      const float* ip = i2h + ((size_t)bz * HW + pixel) * 192;
      float rg = sigmoidf_(acc[0][pt][r] + ip[c] + bir + brr);
      float ug = sigmoidf_(acc[1][pt][r] + ip[64 + c] + biu + bru);
      float mg = tanhf((ip[128 + c] + bim) + rg * (acc[2][pt][r] + brm));
      ob[pixel] = ug * hb[pixel] + (1.f - ug) * mg;
    }
  }
}

extern "C" void kernel_launch(void* const* d_in, const int* in_sizes, int n_in,
                              void* d_out, int out_size, void* d_ws, size_t ws_size,
                              hipStream_t stream) {
  const float* x       = (const float*)d_in[0];
  const float* h       = (const float*)d_in[1];
  const float* w_i2f   = (const float*)d_in[2];
  const float* b_i2f   = (const float*)d_in[3];
  const float* w_h2f   = (const float*)d_in[4];
  const float* b_h2f   = (const float*)d_in[5];
  const float* w_flows = (const float*)d_in[6];
  const float* b_flows = (const float*)d_in[7];
  const float* w_i2h   = (const float*)d_in[8];
  const float* b_i2h   = (const float*)d_in[9];
  const float* w_ret   = (const float*)d_in[10];
  const float* b_ret   = (const float*)d_in[11];
  float* out           = (float*)d_out;
  char* ws = (char*)d_ws;

  __hip_bfloat16* catT   = (__hip_bfloat16*)(ws);             // 25,165,824
  __hip_bfloat16* f_T    = (__hip_bfloat16*)(ws + 25165824);  // 8,388,608
  __hip_bfloat16* warped = (__hip_bfloat16*)(ws);             // 41,943,040 (overlays catT/f_T)
  float* i2hb            = (float*)(ws + 41943040);           // 50,331,648
  float* flows           = (float*)(ws + 92274688);           // 5,242,880
  __hip_bfloat16* packed = (__hip_bfloat16*)(ws + 97517568);  // 122,880
  __hip_bfloat16* pfg    = (__hip_bfloat16*)(ws + 97640448);  // 153,600
  __hip_bfloat16* pfl    = (__hip_bfloat16*)(ws + 97794048);  // 25,600

  k_transpose<<<dim3(256, 8), 256, 0, stream>>>(h, x, catT);
  k_prep_fg<<<300, 256, 0, stream>>>(w_i2f, w_h2f, pfg);
  k_prep_fl<<<50, 256, 0, stream>>>(w_flows, pfl);
  k_prep<<<240, 256, 0, stream>>>(w_ret, packed);

  k_flowgen_mfma<<<dim3(256, 8), 256, 0, stream>>>(catT, pfg, b_i2f, b_h2f, f_T);
  k_flows_mfma<<<dim3(256, 8), 256, 0, stream>>>(f_T, pfl, b_flows, flows);

  for (int b0 = 0; b0 < 8; b0 += 4) {
    k_warp<<<dim3(64, 5, 4), 256, 0, stream>>>(h, flows, warped, b0);
    k_i2h<<<dim3(64, 12, 4), 256, 0, stream>>>(x, w_i2h, i2hb, b0);
    k_gemm_gate<<<dim3(256, 1, 4), 256, 0, stream>>>(warped, packed, i2hb, h,
                                                     b_i2h, b_ret, out, b0);
  }
}

// Round 6
// 365.200 us; speedup vs baseline: 4.2749x; 1.2999x over previous
//
#include <hip/hip_runtime.h>
#include <hip/hip_bf16.h>

// TrajGRU cell, B=8, Cin=8, Ch=64, H=W=128, L=5. Inputs f32, OUTPUT f32.
// All matmul-shaped work on bf16 MFMA (16x16x32):
//   k_transpose    : cat_T[b][p][96] = [h(64), x(8), pad24] bf16 ; x_T[b][p][32]
//   k_prep_*       : weights -> MFMA-fragment-packed bf16
//   k_flowgen_mfma : f_T[b][p][32] = tanh(25-tap implicit GEMM, K=96)   bf16
//   k_flows_mfma   : flows[b][10][p] = 25-tap implicit GEMM, K=32       f32
//   k_warp         : warped_T[b][p][320] = bilinear(h, grid-flow)       bf16
//   k_gemm_gate    : h2h 1x1 GEMM (K=320) + i2h 3x3 implicit GEMM (K=32,
//                    9 taps, m-gate i2h in separate acc) + GRU gate -> out f32
//
// ws layout (proven ws_size >= 134,340,608 from R2):
//   [0)          catT 25,165,824 | f_T @25,165,824 (+8,388,608)  (dead after flows)
//   [0)          warped 83,886,080 (NB=8, overlays catT/f_T after k_flows)
//   [83,886,080) flows   5,242,880
//   [89,128,960) x_T     8,388,608
//   [97,517,568) packed_ret 122,880 | [97,640,448) pfg 153,600
//   [97,794,048) pfl 25,600         | [97,819,648) pih 110,592 -> end 97,930,240

#define HW 16384
#define W_ 128

typedef __attribute__((ext_vector_type(8))) short short8;
typedef __attribute__((ext_vector_type(4))) float f32x4;

__device__ __forceinline__ float sigmoidf_(float z) { return 1.f / (1.f + expf(-z)); }

__device__ __forceinline__ short bf16bits(float v) {
  __hip_bfloat16 bv = __float2bfloat16(v);
  return (short)*reinterpret_cast<unsigned short*>(&bv);
}

// ---- cat_T[b][p][96] (h,x,0) + x_T[b][p][32] (x,0)
__global__ __launch_bounds__(256) void k_transpose(
    const float* __restrict__ h, const float* __restrict__ x,
    __hip_bfloat16* __restrict__ cat, __hip_bfloat16* __restrict__ xT) {
  const int b = blockIdx.y;
  const int wv = threadIdx.x >> 6, l = threadIdx.x & 63;
  const int p = blockIdx.x * 64 + l;
  const int c0 = wv * 24;
  short8 v[3];
#pragma unroll
  for (int q = 0; q < 3; ++q)
#pragma unroll
    for (int k = 0; k < 8; ++k) {
      int c = c0 + q * 8 + k;
      float val = 0.f;
      if (c < 64)      val = h[((size_t)(b * 64 + c) << 14) + p];
      else if (c < 72) val = x[((size_t)(b * 8 + (c - 64)) << 14) + p];
      v[q][k] = bf16bits(val);
    }
  short8* dst = reinterpret_cast<short8*>(cat + ((size_t)b * HW + p) * 96 + c0);
#pragma unroll
  for (int q = 0; q < 3; ++q) dst[q] = v[q];

  // x_T: wave wv writes channels wv*8..+7 (only wv==0 nonzero)
  short8 xv;
#pragma unroll
  for (int k = 0; k < 8; ++k)
    xv[k] = (wv == 0) ? bf16bits(x[((size_t)(b * 8 + k) << 14) + p]) : (short)0;
  reinterpret_cast<short8*>(xT + ((size_t)b * HW + p) * 32)[wv] = xv;
}

// ---- flowgen weights: pfg[(((tap*3+ks)*2+ot)*64+l)*8+i]
__global__ void k_prep_fg(const float* __restrict__ w_i2f,
                          const float* __restrict__ w_h2f,
                          __hip_bfloat16* __restrict__ pfg) {
  int t = blockIdx.x * 256 + threadIdx.x;
  if (t >= 76800) return;
  int i = t & 7, l = (t >> 3) & 63, ot = (t >> 9) & 1, r = t >> 10;
  int ks = r % 3, tap = r / 3;
  int oc = ot * 16 + (l & 15), k = ks * 32 + ((l >> 4) << 3) + i;
  float v = 0.f;
  if (k < 64)      v = w_h2f[(size_t)(oc * 64 + k) * 25 + tap];
  else if (k < 72) v = w_i2f[(size_t)(oc * 8 + (k - 64)) * 25 + tap];
  pfg[t] = __float2bfloat16(v);
}

// ---- flows weights: pfl[((tap*64)+l)*8+i]
__global__ void k_prep_fl(const float* __restrict__ w_flows,
                          __hip_bfloat16* __restrict__ pfl) {
  int t = blockIdx.x * 256 + threadIdx.x;
  if (t >= 12800) return;
  int i = t & 7, l = (t >> 3) & 63, tap = t >> 9;
  int oc = l & 15, k = ((l >> 4) << 3) + i;
  pfl[t] = __float2bfloat16(oc < 10 ? w_flows[(size_t)(oc * 32 + k) * 25 + tap] : 0.f);
}

// ---- w_ret: packed[((mt*10+ks)*64+l)*8+i] (validated)
__global__ void k_prep(const float* __restrict__ w_ret,
                       __hip_bfloat16* __restrict__ packed) {
  int t = blockIdx.x * 256 + threadIdx.x;
  if (t >= 61440) return;
  int i = t & 7, l = (t >> 3) & 63, ks = (t >> 9) % 10, mt = t / 5120;
  int m = mt * 16 + (l & 15), k = ks * 32 + ((l >> 4) << 3) + i;
  packed[t] = __float2bfloat16(w_ret[(size_t)m * 320 + k]);
}

// ---- w_i2h: pih[((tap*12+mt)*64+l)*8+i] = bf16(w_i2h[m][k][tap]), k<8 else 0
__global__ void k_prep_ih(const float* __restrict__ w_i2h,
                          __hip_bfloat16* __restrict__ pih) {
  int t = blockIdx.x * 256 + threadIdx.x;
  if (t >= 55296) return;
  int i = t & 7, l = (t >> 3) & 63, mt = (t >> 9) % 12, tap = t / 6144;
  int m = mt * 16 + (l & 15), k = ((l >> 4) << 3) + i;
  pih[t] = __float2bfloat16(k < 8 ? w_i2h[(size_t)(m * 8 + k) * 9 + tap] : 0.f);
}

// ---- flowgen: 25-tap implicit GEMM, K=96, branchless + fully unrolled
__global__ __launch_bounds__(256) void k_flowgen_mfma(
    const __hip_bfloat16* __restrict__ cat, const __hip_bfloat16* __restrict__ pfg,
    const float* __restrict__ b_i2f, const float* __restrict__ b_h2f,
    __hip_bfloat16* __restrict__ f_T) {
  const int b = blockIdx.y;
  const int y = blockIdx.x >> 1, x0 = (blockIdx.x & 1) << 6;
  const int wv = threadIdx.x >> 6, l = threadIdx.x & 63;
  const int lr = l & 15, lq = l >> 4;
  const int xa = x0 + wv * 16 + lr;
  const short8* cat8 = reinterpret_cast<const short8*>(cat + (size_t)b * HW * 96);
  const short8* pf = reinterpret_cast<const short8*>(pfg);
  const short8 z8 = {0, 0, 0, 0, 0, 0, 0, 0};

  f32x4 acc[2] = {{0.f, 0.f, 0.f, 0.f}, {0.f, 0.f, 0.f, 0.f}};

#pragma unroll
  for (int tap = 0; tap < 25; ++tap) {
    const int dy = tap / 5 - 2, dx = tap % 5 - 2;
    const int yy = y + dy, xx = xa + dx;
    const bool ok = ((unsigned)yy < 128u) && ((unsigned)xx < 128u);
    const int yc = min(max(yy, 0), 127), xc = min(max(xx, 0), 127);
    const short8* ap = cat8 + (size_t)(yc * W_ + xc) * 12 + lq;
#pragma unroll
    for (int ks = 0; ks < 3; ++ks) {
      short8 araw = ap[ks * 4];
      short8 af = ok ? araw : z8;
#pragma unroll
      for (int ot = 0; ot < 2; ++ot) {
        short8 bf = pf[(size_t)(((tap * 3 + ks) << 1) + ot) * 64 + l];
        acc[ot] = __builtin_amdgcn_mfma_f32_16x16x32_bf16(af, bf, acc[ot], 0, 0, 0);
      }
    }
  }

  const int pbase = y * W_ + x0 + wv * 16 + lq * 4;
#pragma unroll
  for (int ot = 0; ot < 2; ++ot) {
    const int oc = ot * 16 + lr;
    const float bias = b_i2f[oc] + b_h2f[oc];
#pragma unroll
    for (int r = 0; r < 4; ++r)
      f_T[((size_t)b * HW + pbase + r) * 32 + oc] =
          __float2bfloat16(tanhf(acc[ot][r] + bias));
  }
}

// ---- flows: 25-tap implicit GEMM, K=32, branchless + unrolled
__global__ __launch_bounds__(256) void k_flows_mfma(
    const __hip_bfloat16* __restrict__ f_T, const __hip_bfloat16* __restrict__ pfl,
    const float* __restrict__ b_flows, float* __restrict__ flows) {
  const int b = blockIdx.y;
  const int y = blockIdx.x >> 1, x0 = (blockIdx.x & 1) << 6;
  const int wv = threadIdx.x >> 6, l = threadIdx.x & 63;
  const int lr = l & 15, lq = l >> 4;
  const int xa = x0 + wv * 16 + lr;
  const short8* ft8 = reinterpret_cast<const short8*>(f_T + (size_t)b * HW * 32);
  const short8* pf = reinterpret_cast<const short8*>(pfl);
  const short8 z8 = {0, 0, 0, 0, 0, 0, 0, 0};

  f32x4 acc = {0.f, 0.f, 0.f, 0.f};

#pragma unroll
  for (int tap = 0; tap < 25; ++tap) {
    const int dy = tap / 5 - 2, dx = tap % 5 - 2;
    const int yy = y + dy, xx = xa + dx;
    const bool ok = ((unsigned)yy < 128u) && ((unsigned)xx < 128u);
    const int yc = min(max(yy, 0), 127), xc = min(max(xx, 0), 127);
    short8 araw = ft8[(size_t)(yc * W_ + xc) * 4 + lq];
    short8 af = ok ? araw : z8;
    short8 bf = pf[tap * 64 + l];
    acc = __builtin_amdgcn_mfma_f32_16x16x32_bf16(af, bf, acc, 0, 0, 0);
  }

  if (lr < 10) {
    const float bb = b_flows[lr];
    const int p = y * W_ + x0 + wv * 16 + lq * 4;
    f32x4 v = {acc[0] + bb, acc[1] + bb, acc[2] + bb, acc[3] + bb};
    *reinterpret_cast<f32x4*>(flows + ((size_t)(b * 10 + lr) << 14) + p) = v;
  }
}

// ---- warp (validated)
__global__ __launch_bounds__(256) void k_warp(
    const float* __restrict__ h, const float* __restrict__ flows,
    __hip_bfloat16* __restrict__ warped) {
  const int b = blockIdx.z;
  const int l = blockIdx.y;
  const int ty0 = (blockIdx.x >> 3) << 4, tx0 = (blockIdx.x & 7) << 4;
  const int lx = threadIdx.x & 15, ly = threadIdx.x >> 4;
  const int ox = tx0 + lx, oy = ty0 + ly;
  const int p = oy * W_ + ox;

  float fx = flows[((size_t)(b * 10 + 2 * l) << 14) + p];
  float fy = flows[((size_t)(b * 10 + 2 * l + 1) << 14) + p];
  float px = fminf(fmaxf((float)ox - fx, 0.f), 127.f);
  float py = fminf(fmaxf((float)oy - fy, 0.f), 127.f);
  float x0f = floorf(px), y0f = floorf(py);
  float wx = px - x0f, wy = py - y0f;
  int x0 = (int)x0f, y0 = (int)y0f;
  int x1 = min(x0 + 1, 127), y1 = min(y0 + 1, 127);
  float w00 = (1.f - wx) * (1.f - wy), w01 = wx * (1.f - wy);
  float w10 = (1.f - wx) * wy, w11 = wx * wy;
  int o00 = y0 * W_ + x0, o01 = y0 * W_ + x1;
  int o10 = y1 * W_ + x0, o11 = y1 * W_ + x1;

  const float* hb = h + ((size_t)(b * 64) << 14);
  __hip_bfloat16* wp = warped + ((size_t)b * HW + p) * 320 + l * 64;
  for (int c0 = 0; c0 < 64; c0 += 8) {
    short8 pack;
#pragma unroll
    for (int k = 0; k < 8; ++k) {
      const float* hp = hb + ((size_t)(c0 + k) << 14);
      pack[k] = bf16bits(hp[o00] * w00 + hp[o01] * w01 + hp[o10] * w10 + hp[o11] * w11);
    }
    *reinterpret_cast<short8*>(wp + c0) = pack;
  }
}

// ---- h2h GEMM (K=320) + fused i2h 3x3 implicit GEMM (K=32) + GRU gating.
// acc[g][pt]: g=0 reset(h2h+i2h), g=1 update(h2h+i2h), g=2 h2h-memory;
// accm[pt]: i2h-memory (kept separate: mg = tanh(i2h_m + r*h2h_m)).
__global__ __launch_bounds__(256) void k_gemm_gate(
    const __hip_bfloat16* __restrict__ warped,
    const __hip_bfloat16* __restrict__ packed,
    const __hip_bfloat16* __restrict__ pih,
    const __hip_bfloat16* __restrict__ xT,
    const float* __restrict__ h,
    const float* __restrict__ b_i2h, const float* __restrict__ b_ret,
    float* __restrict__ out) {
  const int b = blockIdx.z;
  const int p0 = blockIdx.x << 6;
  const int y = p0 >> 7, x0 = p0 & 127;
  const int wv = threadIdx.x >> 6, l = threadIdx.x & 63;
  const int lr = l & 15, lq = l >> 4;

  f32x4 acc[3][4], accm[4];
#pragma unroll
  for (int g = 0; g < 3; ++g)
#pragma unroll
    for (int t = 0; t < 4; ++t) acc[g][t] = {0.f, 0.f, 0.f, 0.f};
#pragma unroll
  for (int t = 0; t < 4; ++t) accm[t] = {0.f, 0.f, 0.f, 0.f};

  // h2h part (validated)
  const short8* ap0 = reinterpret_cast<const short8*>(
      warped + ((size_t)b * HW + p0 + lr) * 320 + lq * 8);
  const short8* bp0 = reinterpret_cast<const short8*>(packed) + (size_t)wv * 640 + l;

  for (int ks = 0; ks < 10; ++ks) {
    short8 af[4];
#pragma unroll
    for (int pt = 0; pt < 4; ++pt) af[pt] = ap0[pt * 640 + ks * 4];
    short8 bf[3];
#pragma unroll
    for (int g = 0; g < 3; ++g) bf[g] = bp0[g * 2560 + ks * 64];
#pragma unroll
    for (int g = 0; g < 3; ++g)
#pragma unroll
      for (int pt = 0; pt < 4; ++pt)
        acc[g][pt] = __builtin_amdgcn_mfma_f32_16x16x32_bf16(af[pt], bf[g],
                                                             acc[g][pt], 0, 0, 0);
  }

  // i2h part: 9-tap implicit GEMM over x_T (K=32, 8 used)
  const short8* xb = reinterpret_cast<const short8*>(xT + (size_t)b * HW * 32);
  const short8* pi = reinterpret_cast<const short8*>(pih);
  const short8 z8 = {0, 0, 0, 0, 0, 0, 0, 0};
#pragma unroll
  for (int tap = 0; tap < 9; ++tap) {
    const int dy = tap / 3 - 1, dx = tap % 3 - 1;
    const int yy = y + dy;
    const bool yok = (unsigned)yy < 128u;
    const int ycl = min(max(yy, 0), 127);
    short8 bf[3];
#pragma unroll
    for (int g = 0; g < 3; ++g) bf[g] = pi[(size_t)(tap * 12 + g * 4 + wv) * 64 + l];
#pragma unroll
    for (int pt = 0; pt < 4; ++pt) {
      const int xx = x0 + pt * 16 + lr + dx;
      const bool ok = yok && ((unsigned)xx < 128u);
      const int xcl = min(max(xx, 0), 127);
      short8 araw = xb[(size_t)(ycl * W_ + xcl) * 4 + lq];
      short8 af = ok ? araw : z8;
      acc[0][pt] = __builtin_amdgcn_mfma_f32_16x16x32_bf16(af, bf[0], acc[0][pt], 0, 0, 0);
      acc[1][pt] = __builtin_amdgcn_mfma_f32_16x16x32_bf16(af, bf[1], acc[1][pt], 0, 0, 0);
      accm[pt]   = __builtin_amdgcn_mfma_f32_16x16x32_bf16(af, bf[2], accm[pt], 0, 0, 0);
    }
  }

  const int c = wv * 16 + lr;
  const float bir = b_i2h[c], biu = b_i2h[64 + c], bim = b_i2h[128 + c];
  const float brr = b_ret[c], bru = b_ret[64 + c], brm = b_ret[128 + c];
  const float* hb = h + ((size_t)(b * 64 + c) << 14);
  float* ob = out + ((size_t)(b * 64 + c) << 14);
#pragma unroll
  for (int pt = 0; pt < 4; ++pt) {
#pragma unroll
    for (int r = 0; r < 4; ++r) {
      const int pixel = p0 + pt * 16 + lq * 4 + r;
      float rg = sigmoidf_(acc[0][pt][r] + bir + brr);
      float ug = sigmoidf_(acc[1][pt][r] + biu + bru);
      float mg = tanhf((accm[pt][r] + bim) + rg * (acc[2][pt][r] + brm));
      ob[pixel] = ug * hb[pixel] + (1.f - ug) * mg;
    }
  }
}

extern "C" void kernel_launch(void* const* d_in, const int* in_sizes, int n_in,
                              void* d_out, int out_size, void* d_ws, size_t ws_size,
                              hipStream_t stream) {
  const float* x       = (const float*)d_in[0];
  const float* h       = (const float*)d_in[1];
  const float* w_i2f   = (const float*)d_in[2];
  const float* b_i2f   = (const float*)d_in[3];
  const float* w_h2f   = (const float*)d_in[4];
  const float* b_h2f   = (const float*)d_in[5];
  const float* w_flows = (const float*)d_in[6];
  const float* b_flows = (const float*)d_in[7];
  const float* w_i2h   = (const float*)d_in[8];
  const float* b_i2h   = (const float*)d_in[9];
  const float* w_ret   = (const float*)d_in[10];
  const float* b_ret   = (const float*)d_in[11];
  float* out           = (float*)d_out;
  char* ws = (char*)d_ws;

  __hip_bfloat16* catT   = (__hip_bfloat16*)(ws);             // 25,165,824
  __hip_bfloat16* f_T    = (__hip_bfloat16*)(ws + 25165824);  // 8,388,608
  __hip_bfloat16* warped = (__hip_bfloat16*)(ws);             // 83,886,080 (overlays catT/f_T)
  float* flows           = (float*)(ws + 83886080);           // 5,242,880
  __hip_bfloat16* xT     = (__hip_bfloat16*)(ws + 89128960);  // 8,388,608
  __hip_bfloat16* packed = (__hip_bfloat16*)(ws + 97517568);  // 122,880
  __hip_bfloat16* pfg    = (__hip_bfloat16*)(ws + 97640448);  // 153,600
  __hip_bfloat16* pfl    = (__hip_bfloat16*)(ws + 97794048);  // 25,600
  __hip_bfloat16* pih    = (__hip_bfloat16*)(ws + 97819648);  // 110,592

  k_transpose<<<dim3(256, 8), 256, 0, stream>>>(h, x, catT, xT);
  k_prep_fg<<<300, 256, 0, stream>>>(w_i2f, w_h2f, pfg);
  k_prep_fl<<<50, 256, 0, stream>>>(w_flows, pfl);
  k_prep<<<240, 256, 0, stream>>>(w_ret, packed);
  k_prep_ih<<<216, 256, 0, stream>>>(w_i2h, pih);

  k_flowgen_mfma<<<dim3(256, 8), 256, 0, stream>>>(catT, pfg, b_i2f, b_h2f, f_T);
  k_flows_mfma<<<dim3(256, 8), 256, 0, stream>>>(f_T, pfl, b_flows, flows);

  k_warp<<<dim3(64, 5, 8), 256, 0, stream>>>(h, flows, warped);
  k_gemm_gate<<<dim3(256, 1, 8), 256, 0, stream>>>(warped, packed, pih, xT, h,
                                                   b_i2h, b_ret, out);
}

// Round 7
// 342.390 us; speedup vs baseline: 4.5597x; 1.0666x over previous
//
#include <hip/hip_runtime.h>
#include <hip/hip_bf16.h>

// TrajGRU cell, B=8, Cin=8, Ch=64, H=W=128, L=5. Inputs f32, OUTPUT f32.
// All matmul-shaped work on bf16 MFMA (16x16x32):
//   k_transpose    : cat_T[b][p][96] = [h(64), x(8), pad24] bf16 ; x_T[b][p][32]
//   k_prep_*       : weights -> MFMA-fragment-packed bf16
//   k_flowgen_mfma : f_T[b][p][32] = tanh(25-tap implicit GEMM, K=96)   bf16
//   k_flows_mfma   : flows[b][10][p] = 25-tap implicit GEMM, K=32       f32
//   k_warp         : warped_T[b][p][320] = bilinear(h, grid-flow)       bf16
//                    (64 px x 320 ch per block; LDS-staged coalesced write,
//                     h read once for all 5 flows)
//   k_gemm_gate    : h2h 1x1 GEMM (K=320) + i2h 3x3 implicit GEMM + gate -> f32
//
// ws layout (proven ws_size >= 134,340,608 from R2):
//   [0)          catT 25,165,824 | f_T @25,165,824 (+8,388,608)  (dead after flows)
//   [0)          warped 83,886,080 (overlays catT/f_T after k_flows)
//   [83,886,080) flows   5,242,880
//   [89,128,960) x_T     8,388,608
//   [97,517,568) packed_ret 122,880 | [97,640,448) pfg 153,600
//   [97,794,048) pfl 25,600         | [97,819,648) pih 110,592 -> end 97,930,240

#define HW 16384
#define W_ 128

typedef __attribute__((ext_vector_type(8))) short short8;
typedef __attribute__((ext_vector_type(4))) float f32x4;
typedef __attribute__((ext_vector_type(4))) unsigned int u32x4;

__device__ __forceinline__ float sigmoidf_(float z) { return 1.f / (1.f + expf(-z)); }

__device__ __forceinline__ short bf16bits(float v) {
  __hip_bfloat16 bv = __float2bfloat16(v);
  return (short)*reinterpret_cast<unsigned short*>(&bv);
}
__device__ __forceinline__ unsigned int bf16u(float v) {
  __hip_bfloat16 bv = __float2bfloat16(v);
  return (unsigned int)*reinterpret_cast<unsigned short*>(&bv);
}

// ---- cat_T[b][p][96] (h,x,0) + x_T[b][p][32] (x,0)
__global__ __launch_bounds__(256) void k_transpose(
    const float* __restrict__ h, const float* __restrict__ x,
    __hip_bfloat16* __restrict__ cat, __hip_bfloat16* __restrict__ xT) {
  const int b = blockIdx.y;
  const int wv = threadIdx.x >> 6, l = threadIdx.x & 63;
  const int p = blockIdx.x * 64 + l;
  const int c0 = wv * 24;
  short8 v[3];
#pragma unroll
  for (int q = 0; q < 3; ++q)
#pragma unroll
    for (int k = 0; k < 8; ++k) {
      int c = c0 + q * 8 + k;
      float val = 0.f;
      if (c < 64)      val = h[((size_t)(b * 64 + c) << 14) + p];
      else if (c < 72) val = x[((size_t)(b * 8 + (c - 64)) << 14) + p];
      v[q][k] = bf16bits(val);
    }
  short8* dst = reinterpret_cast<short8*>(cat + ((size_t)b * HW + p) * 96 + c0);
#pragma unroll
  for (int q = 0; q < 3; ++q) dst[q] = v[q];

  short8 xv;
#pragma unroll
  for (int k = 0; k < 8; ++k)
    xv[k] = (wv == 0) ? bf16bits(x[((size_t)(b * 8 + k) << 14) + p]) : (short)0;
  reinterpret_cast<short8*>(xT + ((size_t)b * HW + p) * 32)[wv] = xv;
}

// ---- flowgen weights: pfg[(((tap*3+ks)*2+ot)*64+l)*8+i]
__global__ void k_prep_fg(const float* __restrict__ w_i2f,
                          const float* __restrict__ w_h2f,
                          __hip_bfloat16* __restrict__ pfg) {
  int t = blockIdx.x * 256 + threadIdx.x;
  if (t >= 76800) return;
  int i = t & 7, l = (t >> 3) & 63, ot = (t >> 9) & 1, r = t >> 10;
  int ks = r % 3, tap = r / 3;
  int oc = ot * 16 + (l & 15), k = ks * 32 + ((l >> 4) << 3) + i;
  float v = 0.f;
  if (k < 64)      v = w_h2f[(size_t)(oc * 64 + k) * 25 + tap];
  else if (k < 72) v = w_i2f[(size_t)(oc * 8 + (k - 64)) * 25 + tap];
  pfg[t] = __float2bfloat16(v);
}

// ---- flows weights: pfl[((tap*64)+l)*8+i]
__global__ void k_prep_fl(const float* __restrict__ w_flows,
                          __hip_bfloat16* __restrict__ pfl) {
  int t = blockIdx.x * 256 + threadIdx.x;
  if (t >= 12800) return;
  int i = t & 7, l = (t >> 3) & 63, tap = t >> 9;
  int oc = l & 15, k = ((l >> 4) << 3) + i;
  pfl[t] = __float2bfloat16(oc < 10 ? w_flows[(size_t)(oc * 32 + k) * 25 + tap] : 0.f);
}

// ---- w_ret: packed[((mt*10+ks)*64+l)*8+i] (validated)
__global__ void k_prep(const float* __restrict__ w_ret,
                       __hip_bfloat16* __restrict__ packed) {
  int t = blockIdx.x * 256 + threadIdx.x;
  if (t >= 61440) return;
  int i = t & 7, l = (t >> 3) & 63, ks = (t >> 9) % 10, mt = t / 5120;
  int m = mt * 16 + (l & 15), k = ks * 32 + ((l >> 4) << 3) + i;
  packed[t] = __float2bfloat16(w_ret[(size_t)m * 320 + k]);
}

// ---- w_i2h: pih[((tap*12+mt)*64+l)*8+i] = bf16(w_i2h[m][k][tap]), k<8 else 0
__global__ void k_prep_ih(const float* __restrict__ w_i2h,
                          __hip_bfloat16* __restrict__ pih) {
  int t = blockIdx.x * 256 + threadIdx.x;
  if (t >= 55296) return;
  int i = t & 7, l = (t >> 3) & 63, mt = (t >> 9) % 12, tap = t / 6144;
  int m = mt * 16 + (l & 15), k = ((l >> 4) << 3) + i;
  pih[t] = __float2bfloat16(k < 8 ? w_i2h[(size_t)(m * 8 + k) * 9 + tap] : 0.f);
}

// ---- flowgen: 25-tap implicit GEMM, K=96, branchless + fully unrolled
__global__ __launch_bounds__(256) void k_flowgen_mfma(
    const __hip_bfloat16* __restrict__ cat, const __hip_bfloat16* __restrict__ pfg,
    const float* __restrict__ b_i2f, const float* __restrict__ b_h2f,
    __hip_bfloat16* __restrict__ f_T) {
  const int b = blockIdx.y;
  const int y = blockIdx.x >> 1, x0 = (blockIdx.x & 1) << 6;
  const int wv = threadIdx.x >> 6, l = threadIdx.x & 63;
  const int lr = l & 15, lq = l >> 4;
  const int xa = x0 + wv * 16 + lr;
  const short8* cat8 = reinterpret_cast<const short8*>(cat + (size_t)b * HW * 96);
  const short8* pf = reinterpret_cast<const short8*>(pfg);
  const short8 z8 = {0, 0, 0, 0, 0, 0, 0, 0};

  f32x4 acc[2] = {{0.f, 0.f, 0.f, 0.f}, {0.f, 0.f, 0.f, 0.f}};

#pragma unroll
  for (int tap = 0; tap < 25; ++tap) {
    const int dy = tap / 5 - 2, dx = tap % 5 - 2;
    const int yy = y + dy, xx = xa + dx;
    const bool ok = ((unsigned)yy < 128u) && ((unsigned)xx < 128u);
    const int yc = min(max(yy, 0), 127), xc = min(max(xx, 0), 127);
    const short8* ap = cat8 + (size_t)(yc * W_ + xc) * 12 + lq;
#pragma unroll
    for (int ks = 0; ks < 3; ++ks) {
      short8 araw = ap[ks * 4];
      short8 af = ok ? araw : z8;
#pragma unroll
      for (int ot = 0; ot < 2; ++ot) {
        short8 bf = pf[(size_t)(((tap * 3 + ks) << 1) + ot) * 64 + l];
        acc[ot] = __builtin_amdgcn_mfma_f32_16x16x32_bf16(af, bf, acc[ot], 0, 0, 0);
      }
    }
  }

  const int pbase = y * W_ + x0 + wv * 16 + lq * 4;
#pragma unroll
  for (int ot = 0; ot < 2; ++ot) {
    const int oc = ot * 16 + lr;
    const float bias = b_i2f[oc] + b_h2f[oc];
#pragma unroll
    for (int r = 0; r < 4; ++r)
      f_T[((size_t)b * HW + pbase + r) * 32 + oc] =
          __float2bfloat16(tanhf(acc[ot][r] + bias));
  }
}

// ---- flows: 25-tap implicit GEMM, K=32, branchless + unrolled
__global__ __launch_bounds__(256) void k_flows_mfma(
    const __hip_bfloat16* __restrict__ f_T, const __hip_bfloat16* __restrict__ pfl,
    const float* __restrict__ b_flows, float* __restrict__ flows) {
  const int b = blockIdx.y;
  const int y = blockIdx.x >> 1, x0 = (blockIdx.x & 1) << 6;
  const int wv = threadIdx.x >> 6, l = threadIdx.x & 63;
  const int lr = l & 15, lq = l >> 4;
  const int xa = x0 + wv * 16 + lr;
  const short8* ft8 = reinterpret_cast<const short8*>(f_T + (size_t)b * HW * 32);
  const short8* pf = reinterpret_cast<const short8*>(pfl);
  const short8 z8 = {0, 0, 0, 0, 0, 0, 0, 0};

  f32x4 acc = {0.f, 0.f, 0.f, 0.f};

#pragma unroll
  for (int tap = 0; tap < 25; ++tap) {
    const int dy = tap / 5 - 2, dx = tap % 5 - 2;
    const int yy = y + dy, xx = xa + dx;
    const bool ok = ((unsigned)yy < 128u) && ((unsigned)xx < 128u);
    const int yc = min(max(yy, 0), 127), xc = min(max(xx, 0), 127);
    short8 araw = ft8[(size_t)(yc * W_ + xc) * 4 + lq];
    short8 af = ok ? araw : z8;
    short8 bf = pf[tap * 64 + l];
    acc = __builtin_amdgcn_mfma_f32_16x16x32_bf16(af, bf, acc, 0, 0, 0);
  }

  if (lr < 10) {
    const float bb = b_flows[lr];
    const int p = y * W_ + x0 + wv * 16 + lq * 4;
    f32x4 v = {acc[0] + bb, acc[1] + bb, acc[2] + bb, acc[3] + bb};
    *reinterpret_cast<f32x4*>(flows + ((size_t)(b * 10 + lr) << 14) + p) = v;
  }
}

// ---- warp: block = 64 consecutive pixels x all 320 channels.
// Thread (pxl = t&63, g = t>>6): for l=0..4, channels g*16..+15, bilinear into
// LDS [64][161] u32 (bf16 pair; stride 161 -> conflict-free). Then one
// cooperative fully-coalesced 40KB contiguous store.
__global__ __launch_bounds__(256) void k_warp(
    const float* __restrict__ h, const float* __restrict__ flows,
    __hip_bfloat16* __restrict__ warped) {
  const int b = blockIdx.y;
  const int p0 = blockIdx.x << 6;
  const int t = threadIdx.x;
  const int pxl = t & 63, g = t >> 6;
  const int p = p0 + pxl;
  const int ox = p & 127, oy = p >> 7;

  __shared__ unsigned int lds[64 * 161];  // 41,216 B

  const float* hb = h + ((size_t)(b * 64) << 14);

#pragma unroll
  for (int l = 0; l < 5; ++l) {
    float fx = flows[((size_t)(b * 10 + 2 * l) << 14) + p];
    float fy = flows[((size_t)(b * 10 + 2 * l + 1) << 14) + p];
    float px = fminf(fmaxf((float)ox - fx, 0.f), 127.f);
    float py = fminf(fmaxf((float)oy - fy, 0.f), 127.f);
    float x0f = floorf(px), y0f = floorf(py);
    float wx = px - x0f, wy = py - y0f;
    int x0 = (int)x0f, y0 = (int)y0f;
    int x1 = min(x0 + 1, 127), y1 = min(y0 + 1, 127);
    float w00 = (1.f - wx) * (1.f - wy), w01 = wx * (1.f - wy);
    float w10 = (1.f - wx) * wy, w11 = wx * wy;
    int o00 = y0 * W_ + x0, o01 = y0 * W_ + x1;
    int o10 = y1 * W_ + x0, o11 = y1 * W_ + x1;

    unsigned int* lrow = lds + pxl * 161 + l * 32 + g * 8;
#pragma unroll
    for (int kk = 0; kk < 8; ++kk) {
      const float* hp0 = hb + ((size_t)(g * 16 + 2 * kk) << 14);
      const float* hp1 = hp0 + HW;
      float v0 = hp0[o00] * w00 + hp0[o01] * w01 + hp0[o10] * w10 + hp0[o11] * w11;
      float v1 = hp1[o00] * w00 + hp1[o01] * w01 + hp1[o10] * w10 + hp1[o11] * w11;
      lrow[kk] = bf16u(v0) | (bf16u(v1) << 16);
    }
  }
  __syncthreads();

  // 64 px * 640 B = 40 KB contiguous: 2560 x 16B chunks, 10 iterations.
  u32x4* gout = reinterpret_cast<u32x4*>(warped + ((size_t)b * HW + p0) * 320);
#pragma unroll
  for (int iter = 0; iter < 10; ++iter) {
    int idx16 = iter * 256 + t;          // 16B chunk id
    int prow = idx16 / 40, j = idx16 - prow * 40;
    const unsigned int* src = lds + prow * 161 + j * 4;
    u32x4 v = {src[0], src[1], src[2], src[3]};
    gout[idx16] = v;
  }
}

// ---- h2h GEMM (K=320) + fused i2h 3x3 implicit GEMM (K=32) + GRU gating.
__global__ __launch_bounds__(256) void k_gemm_gate(
    const __hip_bfloat16* __restrict__ warped,
    const __hip_bfloat16* __restrict__ packed,
    const __hip_bfloat16* __restrict__ pih,
    const __hip_bfloat16* __restrict__ xT,
    const float* __restrict__ h,
    const float* __restrict__ b_i2h, const float* __restrict__ b_ret,
    float* __restrict__ out) {
  const int b = blockIdx.z;
  const int p0 = blockIdx.x << 6;
  const int y = p0 >> 7, x0 = p0 & 127;
  const int wv = threadIdx.x >> 6, l = threadIdx.x & 63;
  const int lr = l & 15, lq = l >> 4;

  f32x4 acc[3][4], accm[4];
#pragma unroll
  for (int g = 0; g < 3; ++g)
#pragma unroll
    for (int t = 0; t < 4; ++t) acc[g][t] = {0.f, 0.f, 0.f, 0.f};
#pragma unroll
  for (int t = 0; t < 4; ++t) accm[t] = {0.f, 0.f, 0.f, 0.f};

  const short8* ap0 = reinterpret_cast<const short8*>(
      warped + ((size_t)b * HW + p0 + lr) * 320 + lq * 8);
  const short8* bp0 = reinterpret_cast<const short8*>(packed) + (size_t)wv * 640 + l;

  for (int ks = 0; ks < 10; ++ks) {
    short8 af[4];
#pragma unroll
    for (int pt = 0; pt < 4; ++pt) af[pt] = ap0[pt * 640 + ks * 4];
    short8 bf[3];
#pragma unroll
    for (int g = 0; g < 3; ++g) bf[g] = bp0[g * 2560 + ks * 64];
#pragma unroll
    for (int g = 0; g < 3; ++g)
#pragma unroll
      for (int pt = 0; pt < 4; ++pt)
        acc[g][pt] = __builtin_amdgcn_mfma_f32_16x16x32_bf16(af[pt], bf[g],
                                                             acc[g][pt], 0, 0, 0);
  }

  const short8* xb = reinterpret_cast<const short8*>(xT + (size_t)b * HW * 32);
  const short8* pi = reinterpret_cast<const short8*>(pih);
  const short8 z8 = {0, 0, 0, 0, 0, 0, 0, 0};
#pragma unroll
  for (int tap = 0; tap < 9; ++tap) {
    const int dy = tap / 3 - 1, dx = tap % 3 - 1;
    const int yy = y + dy;
    const bool yok = (unsigned)yy < 128u;
    const int ycl = min(max(yy, 0), 127);
    short8 bf[3];
#pragma unroll
    for (int g = 0; g < 3; ++g) bf[g] = pi[(size_t)(tap * 12 + g * 4 + wv) * 64 + l];
#pragma unroll
    for (int pt = 0; pt < 4; ++pt) {
      const int xx = x0 + pt * 16 + lr + dx;
      const bool ok = yok && ((unsigned)xx < 128u);
      const int xcl = min(max(xx, 0), 127);
      short8 araw = xb[(size_t)(ycl * W_ + xcl) * 4 + lq];
      short8 af = ok ? araw : z8;
      acc[0][pt] = __builtin_amdgcn_mfma_f32_16x16x32_bf16(af, bf[0], acc[0][pt], 0, 0, 0);
      acc[1][pt] = __builtin_amdgcn_mfma_f32_16x16x32_bf16(af, bf[1], acc[1][pt], 0, 0, 0);
      accm[pt]   = __builtin_amdgcn_mfma_f32_16x16x32_bf16(af, bf[2], accm[pt], 0, 0, 0);
    }
  }

  const int c = wv * 16 + lr;
  const float bir = b_i2h[c], biu = b_i2h[64 + c], bim = b_i2h[128 + c];
  const float brr = b_ret[c], bru = b_ret[64 + c], brm = b_ret[128 + c];
  const float* hb = h + ((size_t)(b * 64 + c) << 14);
  float* ob = out + ((size_t)(b * 64 + c) << 14);
#pragma unroll
  for (int pt = 0; pt < 4; ++pt) {
#pragma unroll
    for (int r = 0; r < 4; ++r) {
      const int pixel = p0 + pt * 16 + lq * 4 + r;
      float rg = sigmoidf_(acc[0][pt][r] + bir + brr);
      float ug = sigmoidf_(acc[1][pt][r] + biu + bru);
      float mg = tanhf((accm[pt][r] + bim) + rg * (acc[2][pt][r] + brm));
      ob[pixel] = ug * hb[pixel] + (1.f - ug) * mg;
    }
  }
}

extern "C" void kernel_launch(void* const* d_in, const int* in_sizes, int n_in,
                              void* d_out, int out_size, void* d_ws, size_t ws_size,
                              hipStream_t stream) {
  const float* x       = (const float*)d_in[0];
  const float* h       = (const float*)d_in[1];
  const float* w_i2f   = (const float*)d_in[2];
  const float* b_i2f   = (const float*)d_in[3];
  const float* w_h2f   = (const float*)d_in[4];
  const float* b_h2f   = (const float*)d_in[5];
  const float* w_flows = (const float*)d_in[6];
  const float* b_flows = (const float*)d_in[7];
  const float* w_i2h   = (const float*)d_in[8];
  const float* b_i2h   = (const float*)d_in[9];
  const float* w_ret   = (const float*)d_in[10];
  const float* b_ret   = (const float*)d_in[11];
  float* out           = (float*)d_out;
  char* ws = (char*)d_ws;

  __hip_bfloat16* catT   = (__hip_bfloat16*)(ws);             // 25,165,824
  __hip_bfloat16* f_T    = (__hip_bfloat16*)(ws + 25165824);  // 8,388,608
  __hip_bfloat16* warped = (__hip_bfloat16*)(ws);             // 83,886,080 (overlays catT/f_T)
  float* flows           = (float*)(ws + 83886080);           // 5,242,880
  __hip_bfloat16* xT     = (__hip_bfloat16*)(ws + 89128960);  // 8,388,608
  __hip_bfloat16* packed = (__hip_bfloat16*)(ws + 97517568);  // 122,880
  __hip_bfloat16* pfg    = (__hip_bfloat16*)(ws + 97640448);  // 153,600
  __hip_bfloat16* pfl    = (__hip_bfloat16*)(ws + 97794048);  // 25,600
  __hip_bfloat16* pih    = (__hip_bfloat16*)(ws + 97819648);  // 110,592

  k_transpose<<<dim3(256, 8), 256, 0, stream>>>(h, x, catT, xT);
  k_prep_fg<<<300, 256, 0, stream>>>(w_i2f, w_h2f, pfg);
  k_prep_fl<<<50, 256, 0, stream>>>(w_flows, pfl);
  k_prep<<<240, 256, 0, stream>>>(w_ret, packed);
  k_prep_ih<<<216, 256, 0, stream>>>(w_i2h, pih);

  k_flowgen_mfma<<<dim3(256, 8), 256, 0, stream>>>(catT, pfg, b_i2f, b_h2f, f_T);
  k_flows_mfma<<<dim3(256, 8), 256, 0, stream>>>(f_T, pfl, b_flows, flows);

  k_warp<<<dim3(256, 8), 256, 0, stream>>>(h, flows, warped);
  k_gemm_gate<<<dim3(256, 1, 8), 256, 0, stream>>>(warped, packed, pih, xT, h,
                                                   b_i2h, b_ret, out);
}